// Round 4
// baseline (157.875 us; speedup 1.0000x reference)
//
#include <hip/hip_runtime.h>

#define N_NODES 512
#define N_EDGES (512 * 512)

typedef _Float16 h2 __attribute__((ext_vector_type(2)));

__device__ __forceinline__ float fdot2(h2 a, h2 b, float c) {
#if __has_builtin(__builtin_amdgcn_fdot2)
  return __builtin_amdgcn_fdot2(a, b, c, false);
#else
  float r;
  asm("v_dot2_f32_f16 %0, %1, %2, %3" : "=v"(r) : "v"(a), "v"(b), "v"(c));
  return r;
#endif
}

__device__ __forceinline__ unsigned pkf16(float a, float b) {
  return __builtin_bit_cast(unsigned, __builtin_amdgcn_cvt_pkrtz(a, b));
}
__device__ __forceinline__ h2 ash2(unsigned u) { return __builtin_bit_cast(h2, u); }

// ---------------- utility: zero int buffer ----------------
__global__ void zero_k(int* __restrict__ p, int n) {
  int i = blockIdx.x * blockDim.x + threadIdx.x;
  if (i < n) p[i] = 0;
}

// ---------------- histogram of dst ----------------
__global__ void hist_k(const int* __restrict__ dst, int* __restrict__ counts) {
  __shared__ int lh[N_NODES];
  for (int i = threadIdx.x; i < N_NODES; i += blockDim.x) lh[i] = 0;
  __syncthreads();
  const int stride = gridDim.x * blockDim.x;
  for (int e = blockIdx.x * blockDim.x + threadIdx.x; e < N_EDGES; e += stride)
    atomicAdd(&lh[dst[e]], 1);
  __syncthreads();
  for (int i = threadIdx.x; i < N_NODES; i += blockDim.x) {
    int c = lh[i];
    if (c) atomicAdd(&counts[i], c);
  }
}

// ---------------- exclusive scan over 512 counts ----------------
__global__ void scan_k(const int* __restrict__ counts, int* __restrict__ offsets,
                       int* __restrict__ cursor) {
  __shared__ int tmp[N_NODES];
  const int t = threadIdx.x;
  const int c = counts[t];
  tmp[t] = c;
  __syncthreads();
  for (int d = 1; d < N_NODES; d <<= 1) {
    int add = (t >= d) ? tmp[t - d] : 0;
    __syncthreads();
    tmp[t] += add;
    __syncthreads();
  }
  offsets[t + 1] = tmp[t];
  if (t == 0) offsets[0] = 0;
  cursor[t] = tmp[t] - c;
}

// ---------------- low-contention scatter ----------------
__launch_bounds__(512)
__global__ void scatter2_k(const int* __restrict__ dst, int* __restrict__ cursor,
                           int* __restrict__ perm) {
  __shared__ int lhist[N_NODES];
  __shared__ int gb[N_NODES];
  const int t = threadIdx.x;
  const int c0 = blockIdx.x * 4096;
  lhist[t] = 0;
  __syncthreads();
  int d[8], r[8];
#pragma unroll
  for (int j = 0; j < 8; j++) {
    d[j] = dst[c0 + t + j * 512];
    r[j] = atomicAdd(&lhist[d[j]], 1);
  }
  __syncthreads();
  gb[t] = atomicAdd(&cursor[t], lhist[t]);
  __syncthreads();
#pragma unroll
  for (int j = 0; j < 8; j++) perm[gb[d[j]] + r[j]] = c0 + t + j * 512;
}

// ---------------- layer-1 conv (IN=1): edge-parallel, weights in LDS -------
template <int IN, int OUT, int INSTR, int OSTR>
__launch_bounds__(256)
__global__ void conv_k(const float* __restrict__ hprev, const float* __restrict__ ea,
                       const int* __restrict__ src, const int* __restrict__ perm,
                       const int* __restrict__ offsets, const float* __restrict__ W,
                       const float* __restrict__ bvec, const float* __restrict__ root,
                       const float* __restrict__ bias, float* __restrict__ hnext) {
  constexpr int KK = IN * OUT;
  __shared__ float Wt[KK * 8];
  __shared__ float red[4][OUT];
  const int node = blockIdx.x;

  for (int k = threadIdx.x; k < KK; k += blockDim.x) {
#pragma unroll
    for (int v = 0; v < 6; v++) Wt[k * 8 + v] = W[v * KK + k];
    Wt[k * 8 + 6] = bvec[k];
    Wt[k * 8 + 7] = 0.f;
  }
  __syncthreads();

  const int off = offsets[node];
  const int cnt = offsets[node + 1] - off;

  float acc[OUT];
#pragma unroll
  for (int o = 0; o < OUT; o++) acc[o] = 0.f;

  for (int t = threadIdx.x; t < cnt; t += blockDim.x) {
    const int e = perm[off + t];
    const float2 a01 = *reinterpret_cast<const float2*>(ea + e * 6);
    const float2 a23 = *reinterpret_cast<const float2*>(ea + e * 6 + 2);
    const float2 a45 = *reinterpret_cast<const float2*>(ea + e * 6 + 4);
    const int s = src[e];
    const float* hs = hprev + s * INSTR;
#pragma unroll
    for (int i = 0; i < IN; i++) {
      const float hsi = hs[i];
#pragma unroll
      for (int o = 0; o < OUT; o++) {
        const float4 w0 = *reinterpret_cast<const float4*>(&Wt[(i * OUT + o) * 8]);
        const float4 w1 = *reinterpret_cast<const float4*>(&Wt[(i * OUT + o) * 8 + 4]);
        float th = w1.z;
        th = fmaf(a01.x, w0.x, th);
        th = fmaf(a01.y, w0.y, th);
        th = fmaf(a23.x, w0.z, th);
        th = fmaf(a23.y, w0.w, th);
        th = fmaf(a45.x, w1.x, th);
        th = fmaf(a45.y, w1.y, th);
        acc[o] = fmaf(hsi, fmaxf(th, 0.f), acc[o]);
      }
    }
  }

  const int lane = threadIdx.x & 63;
  const int wid = threadIdx.x >> 6;
#pragma unroll
  for (int o = 0; o < OUT; o++) {
    float v = acc[o];
#pragma unroll
    for (int d = 32; d > 0; d >>= 1) v += __shfl_down(v, d, 64);
    if (lane == 0) red[wid][o] = v;
  }
  __syncthreads();

  if (threadIdx.x < OUT) {
    const int o = threadIdx.x;
    float sum = red[0][o] + red[1][o] + red[2][o] + red[3][o];
    float agg = sum / fmaxf((float)cnt, 1.f);
    float r = bias[o];
    for (int i = 0; i < IN; i++) r = fmaf(hprev[node * INSTR + i], root[i * OUT + o], r);
    hnext[node * OSTR + o] = fmaxf(agg + r, 0.f);
  } else if (threadIdx.x < OSTR) {
    hnext[node * OSTR + threadIdx.x] = 0.f;  // zero pad columns
  }
}

// ---------------- big-KK conv v3: f16-packed weights in regs, dot2 math --------
// Lane l owns K_PER consecutive (i,o) pairs (spanning <=2 i values, split at kb).
// Each wave: private 32-edge double-buffered LDS pipeline, T14 async staging.
template <int IN, int HP, int OUT, int OSTR>
__launch_bounds__(256, 2)
__global__ void convR3_k(const float* __restrict__ hprev,  // [N][HP] f32
                         const float* __restrict__ ea, const int* __restrict__ srcA,
                         const int* __restrict__ perm, const int* __restrict__ offsets,
                         const float* __restrict__ W,      // [6][IN*OUT] f32
                         const float* __restrict__ bvec, const float* __restrict__ root,
                         const float* __restrict__ bias,
                         float* __restrict__ hnext) {      // [N][OSTR]
  constexpr int NPAIR = IN * OUT;
  constexpr int K_PER = (NPAIR + 63) / 64;
  constexpr int B = 32;
  constexpr int F4 = HP / 8;  // float4 per half h-row

  __shared__ unsigned eaS[4][2][B][4];   // 3 packed f16x2 + pad
  __shared__ float hS[4][2][B][HP];
  __shared__ float pAcc[4][NPAIR];

  const int tid = threadIdx.x;
  const int wid = tid >> 6;
  const int l = tid & 63;
  const int node = blockIdx.x;
  const int off = offsets[node];
  const int cnt = offsets[node + 1] - off;

  // ---- per-lane pair slice ----
  const int p0 = l * K_PER;
  const int i0 = min(p0, NPAIR - 1) / OUT;
  const int i1 = min(i0 + 1, IN - 1);
  const int kb = (i0 + 1) * OUT - p0;  // k < kb -> h[i0], else h[i1]
  unsigned w01[K_PER], w23[K_PER], w45[K_PER];
  float wb[K_PER], acc[K_PER];
#pragma unroll
  for (int k = 0; k < K_PER; k++) {
    const int p = min(p0 + k, NPAIR - 1);
    h2 a, b, c;
    a[0] = (_Float16)W[0 * NPAIR + p]; a[1] = (_Float16)W[1 * NPAIR + p];
    b[0] = (_Float16)W[2 * NPAIR + p]; b[1] = (_Float16)W[3 * NPAIR + p];
    c[0] = (_Float16)W[4 * NPAIR + p]; c[1] = (_Float16)W[5 * NPAIR + p];
    w01[k] = __builtin_bit_cast(unsigned, a);
    w23[k] = __builtin_bit_cast(unsigned, b);
    w45[k] = __builtin_bit_cast(unsigned, c);
    wb[k] = bvec[p];
    acc[k] = 0.f;
  }

  const int NB = (cnt + B - 1) / B;

  // ---- T14 async staging: load-to-reg early, ds_write late ----
  const int sb = l >> 1, sq = l & 1;
  float2 la0, la1, la2;
  float4 lh[F4];
  bool lok = false;

  auto stage_load = [&](int m) {
    const int pos = m * B + sb;
    lok = (pos < cnt);
    if (lok) {
      const int e = perm[off + pos];
      if (sq == 0) {
        const float2* er = reinterpret_cast<const float2*>(ea + (size_t)e * 6);
        la0 = er[0]; la1 = er[1]; la2 = er[2];
      }
      const int s = srcA[e];
      const float4* hr = reinterpret_cast<const float4*>(hprev + (size_t)s * HP);
#pragma unroll
      for (int j = 0; j < F4; j++) lh[j] = hr[sq * F4 + j];
    }
  };
  auto stage_write = [&](int buf) {
    if (lok) {
      if (sq == 0) {
        uint4 pk;
        pk.x = pkf16(la0.x, la0.y);
        pk.y = pkf16(la1.x, la1.y);
        pk.z = pkf16(la2.x, la2.y);
        pk.w = 0u;
        *reinterpret_cast<uint4*>(&eaS[wid][buf][sb][0]) = pk;
      }
#pragma unroll
      for (int j = 0; j < F4; j++)
        *reinterpret_cast<float4*>(&hS[wid][buf][sb][sq * (HP / 2) + 4 * j]) = lh[j];
    }
  };

  if (wid < NB) { stage_load(wid); stage_write(0); }
  int buf = 0;
  for (int m = wid; m < NB; m += 4, buf ^= 1) {
    const bool more = (m + 4 < NB);
    if (more) stage_load(m + 4);
    const int lim = min(B, cnt - m * B);
    for (int b = 0; b < lim; b++) {
      const uint4 eu = *reinterpret_cast<const uint4*>(&eaS[wid][buf][b][0]);
      const h2 a01 = ash2(eu.x), a23 = ash2(eu.y), a45 = ash2(eu.z);
      const float hv0 = hS[wid][buf][b][i0];
      const float hv1 = hS[wid][buf][b][i1];
#pragma unroll
      for (int k = 0; k < K_PER; k++) {
        float th = fdot2(a45, ash2(w45[k]),
                    fdot2(a23, ash2(w23[k]),
                     fdot2(a01, ash2(w01[k]), wb[k])));
        const float hv = (k < kb) ? hv0 : hv1;
        acc[k] = fmaf(hv, fmaxf(th, 0.f), acc[k]);
      }
    }
    if (more) stage_write(buf ^ 1);
  }

  // ---- reduction ----
#pragma unroll
  for (int k = 0; k < K_PER; k++)
    if (p0 + k < NPAIR) pAcc[wid][p0 + k] = acc[k];
  __syncthreads();
  for (int p = tid; p < NPAIR; p += 256)
    pAcc[0][p] = pAcc[0][p] + pAcc[1][p] + pAcc[2][p] + pAcc[3][p];
  __syncthreads();
  if (tid < OUT) {
    const int o = tid;
    float s = 0.f;
    for (int i = 0; i < IN; i++) s += pAcc[0][i * OUT + o];
    const float agg = s / fmaxf((float)cnt, 1.f);
    float r = bias[o];
    for (int i = 0; i < IN; i++) r = fmaf(hprev[(size_t)node * HP + i], root[i * OUT + o], r);
    hnext[(size_t)node * OSTR + o] = fmaxf(agg + r, 0.f);
  }
}

// ---------------- CBT: pairwise L1 over h3 [512, 5] ----------------
__global__ void cbt_k(const float* __restrict__ h3, float* __restrict__ out) {
  __shared__ float sh[N_NODES * 5];
  for (int i = threadIdx.x; i < N_NODES * 5; i += blockDim.x) sh[i] = h3[i];
  __syncthreads();
  const int a = blockIdx.x;
  float ha0 = sh[a * 5 + 0], ha1 = sh[a * 5 + 1], ha2 = sh[a * 5 + 2],
        ha3 = sh[a * 5 + 3], ha4 = sh[a * 5 + 4];
  for (int b = threadIdx.x; b < N_NODES; b += blockDim.x) {
    float s = fabsf(sh[b * 5 + 0] - ha0) + fabsf(sh[b * 5 + 1] - ha1) +
              fabsf(sh[b * 5 + 2] - ha2) + fabsf(sh[b * 5 + 3] - ha3) +
              fabsf(sh[b * 5 + 4] - ha4);
    out[a * N_NODES + b] = s;
  }
}

extern "C" void kernel_launch(void* const* d_in, const int* in_sizes, int n_in,
                              void* d_out, int out_size, void* d_ws, size_t ws_size,
                              hipStream_t stream) {
  const float* x     = (const float*)d_in[0];
  const float* ea    = (const float*)d_in[1];
  const int*   ei    = (const int*)d_in[2];
  const float* W1    = (const float*)d_in[3];
  const float* b1    = (const float*)d_in[4];
  const float* root1 = (const float*)d_in[5];
  const float* bias1 = (const float*)d_in[6];
  const float* W2    = (const float*)d_in[7];
  const float* b2    = (const float*)d_in[8];
  const float* root2 = (const float*)d_in[9];
  const float* bias2 = (const float*)d_in[10];
  const float* W3    = (const float*)d_in[11];
  const float* b3    = (const float*)d_in[12];
  const float* root3 = (const float*)d_in[13];
  const float* bias3 = (const float*)d_in[14];

  const int* src = ei;
  const int* dst = ei + N_EDGES;

  char* ws = (char*)d_ws;
  int* counts  = (int*)(ws + 0);
  int* offsets = (int*)(ws + 8192);
  int* cursor  = (int*)(ws + 16384);
  int* perm    = (int*)(ws + 32768);                 // E ints = 1 MB
  float* h1    = (float*)(ws + 32768 + N_EDGES * 4); // [512][40]
  float* h2_   = h1 + N_NODES * 40;                  // [512][24]
  float* h3    = h2_ + N_NODES * 24;                 // [512][5]

  zero_k<<<2, 256, 0, stream>>>(counts, N_NODES);
  hist_k<<<256, 256, 0, stream>>>(dst, counts);
  scan_k<<<1, N_NODES, 0, stream>>>(counts, offsets, cursor);
  scatter2_k<<<N_EDGES / 4096, 512, 0, stream>>>(dst, cursor, perm);

  // layer 1: IN=1 OUT=36, edge-parallel, output stride 40 (zero-padded)
  conv_k<1, 36, 1, 40><<<N_NODES, 256, 0, stream>>>(x, ea, src, perm, offsets, W1, b1, root1, bias1, h1);
  // layer 2: IN=36 (stride 40) OUT=24: 864 pairs across 64 lanes, f16 dot2
  convR3_k<36, 40, 24, 24><<<N_NODES, 256, 0, stream>>>(h1, ea, src, perm, offsets, W2, b2, root2, bias2, h2_);
  // layer 3: IN=24 OUT=5: 120 pairs, K_PER=2
  convR3_k<24, 24, 5, 5><<<N_NODES, 256, 0, stream>>>(h2_, ea, src, perm, offsets, W3, b3, root3, bias3, h3);

  cbt_k<<<N_NODES, 256, 0, stream>>>(h3, (float*)d_out);
}

// Round 5
// 145.499 us; speedup vs baseline: 1.0851x; 1.0851x over previous
//
#include <hip/hip_runtime.h>

#define N_NODES 512
#define N_EDGES (512 * 512)

typedef _Float16 h2 __attribute__((ext_vector_type(2)));

__device__ __forceinline__ float fdot2(h2 a, h2 b, float c) {
#if __has_builtin(__builtin_amdgcn_fdot2)
  return __builtin_amdgcn_fdot2(a, b, c, false);
#else
  float r;
  asm("v_dot2_f32_f16 %0, %1, %2, %3" : "=v"(r) : "v"(a), "v"(b), "v"(c));
  return r;
#endif
}

__device__ __forceinline__ unsigned pkf16(float a, float b) {
  return __builtin_bit_cast(unsigned, __builtin_amdgcn_cvt_pkrtz(a, b));
}
__device__ __forceinline__ h2 ash2(unsigned u) { return __builtin_bit_cast(h2, u); }

// ---------------- utility: zero int buffer ----------------
__global__ void zero_k(int* __restrict__ p, int n) {
  int i = blockIdx.x * blockDim.x + threadIdx.x;
  if (i < n) p[i] = 0;
}

// ---------------- pack W+bias into f16x2 uint4 per pair ----------------
__global__ void packW_k(const float* __restrict__ W, const float* __restrict__ bvec,
                        uint4* __restrict__ out, int npair) {
  int p = blockIdx.x * 256 + threadIdx.x;
  if (p < npair) {
    uint4 r;
    r.x = pkf16(W[0 * npair + p], W[1 * npair + p]);
    r.y = pkf16(W[2 * npair + p], W[3 * npair + p]);
    r.z = pkf16(W[4 * npair + p], W[5 * npair + p]);
    r.w = __builtin_bit_cast(unsigned, bvec[p]);
    out[p] = r;
  }
}

// ---------------- histogram of dst ----------------
__global__ void hist_k(const int* __restrict__ dst, int* __restrict__ counts) {
  __shared__ int lh[N_NODES];
  for (int i = threadIdx.x; i < N_NODES; i += blockDim.x) lh[i] = 0;
  __syncthreads();
  const int stride = gridDim.x * blockDim.x;
  for (int e = blockIdx.x * blockDim.x + threadIdx.x; e < N_EDGES; e += stride)
    atomicAdd(&lh[dst[e]], 1);
  __syncthreads();
  for (int i = threadIdx.x; i < N_NODES; i += blockDim.x) {
    int c = lh[i];
    if (c) atomicAdd(&counts[i], c);
  }
}

// ---------------- exclusive scan over 512 counts ----------------
__global__ void scan_k(const int* __restrict__ counts, int* __restrict__ offsets,
                       int* __restrict__ cursor) {
  __shared__ int tmp[N_NODES];
  const int t = threadIdx.x;
  const int c = counts[t];
  tmp[t] = c;
  __syncthreads();
  for (int d = 1; d < N_NODES; d <<= 1) {
    int add = (t >= d) ? tmp[t - d] : 0;
    __syncthreads();
    tmp[t] += add;
    __syncthreads();
  }
  offsets[t + 1] = tmp[t];
  if (t == 0) offsets[0] = 0;
  cursor[t] = tmp[t] - c;
}

// ---------------- low-contention scatter ----------------
__launch_bounds__(512)
__global__ void scatter2_k(const int* __restrict__ dst, int* __restrict__ cursor,
                           int* __restrict__ perm) {
  __shared__ int lhist[N_NODES];
  __shared__ int gb[N_NODES];
  const int t = threadIdx.x;
  const int c0 = blockIdx.x * 4096;
  lhist[t] = 0;
  __syncthreads();
  int d[8], r[8];
#pragma unroll
  for (int j = 0; j < 8; j++) {
    d[j] = dst[c0 + t + j * 512];
    r[j] = atomicAdd(&lhist[d[j]], 1);
  }
  __syncthreads();
  gb[t] = atomicAdd(&cursor[t], lhist[t]);
  __syncthreads();
#pragma unroll
  for (int j = 0; j < 8; j++) perm[gb[d[j]] + r[j]] = c0 + t + j * 512;
}

// ---------------- layer-1 conv (IN=1): edge-parallel, weights in LDS -------
template <int IN, int OUT, int INSTR, int OSTR>
__launch_bounds__(256)
__global__ void conv_k(const float* __restrict__ hprev, const float* __restrict__ ea,
                       const int* __restrict__ src, const int* __restrict__ perm,
                       const int* __restrict__ offsets, const float* __restrict__ W,
                       const float* __restrict__ bvec, const float* __restrict__ root,
                       const float* __restrict__ bias, float* __restrict__ hnext) {
  constexpr int KK = IN * OUT;
  __shared__ float Wt[KK * 8];
  __shared__ float red[4][OUT];
  const int node = blockIdx.x;

  for (int k = threadIdx.x; k < KK; k += blockDim.x) {
#pragma unroll
    for (int v = 0; v < 6; v++) Wt[k * 8 + v] = W[v * KK + k];
    Wt[k * 8 + 6] = bvec[k];
    Wt[k * 8 + 7] = 0.f;
  }
  __syncthreads();

  const int off = offsets[node];
  const int cnt = offsets[node + 1] - off;

  float acc[OUT];
#pragma unroll
  for (int o = 0; o < OUT; o++) acc[o] = 0.f;

  for (int t = threadIdx.x; t < cnt; t += blockDim.x) {
    const int e = perm[off + t];
    const float2 a01 = *reinterpret_cast<const float2*>(ea + e * 6);
    const float2 a23 = *reinterpret_cast<const float2*>(ea + e * 6 + 2);
    const float2 a45 = *reinterpret_cast<const float2*>(ea + e * 6 + 4);
    const int s = src[e];
    const float* hs = hprev + s * INSTR;
#pragma unroll
    for (int i = 0; i < IN; i++) {
      const float hsi = hs[i];
#pragma unroll
      for (int o = 0; o < OUT; o++) {
        const float4 w0 = *reinterpret_cast<const float4*>(&Wt[(i * OUT + o) * 8]);
        const float4 w1 = *reinterpret_cast<const float4*>(&Wt[(i * OUT + o) * 8 + 4]);
        float th = w1.z;
        th = fmaf(a01.x, w0.x, th);
        th = fmaf(a01.y, w0.y, th);
        th = fmaf(a23.x, w0.z, th);
        th = fmaf(a23.y, w0.w, th);
        th = fmaf(a45.x, w1.x, th);
        th = fmaf(a45.y, w1.y, th);
        acc[o] = fmaf(hsi, fmaxf(th, 0.f), acc[o]);
      }
    }
  }

  const int lane = threadIdx.x & 63;
  const int wid = threadIdx.x >> 6;
#pragma unroll
  for (int o = 0; o < OUT; o++) {
    float v = acc[o];
#pragma unroll
    for (int d = 32; d > 0; d >>= 1) v += __shfl_down(v, d, 64);
    if (lane == 0) red[wid][o] = v;
  }
  __syncthreads();

  if (threadIdx.x < OUT) {
    const int o = threadIdx.x;
    float sum = red[0][o] + red[1][o] + red[2][o] + red[3][o];
    float agg = sum / fmaxf((float)cnt, 1.f);
    float r = bias[o];
    for (int i = 0; i < IN; i++) r = fmaf(hprev[node * INSTR + i], root[i * OUT + o], r);
    hnext[node * OSTR + o] = fmaxf(agg + r, 0.f);
  } else if (threadIdx.x < OSTR) {
    hnext[node * OSTR + threadIdx.x] = 0.f;  // zero pad columns
  }
}

// ---------------- big-KK conv v4: 8 waves, no h staging, global h gather -------
// Lane l owns K_PER consecutive (i,o) pairs (<=2 i values, split at kb).
// Each wave: private 32-edge double-buffered ea/src LDS pipeline; h values
// gathered per-lane from global (L1/L2-resident), software-pipelined 1 ahead.
template <int IN, int HP, int OUT, int OSTR>
__launch_bounds__(512, 4)
__global__ void convR4_k(const float* __restrict__ hprev,  // [N][HP] f32
                         const float* __restrict__ ea, const int* __restrict__ srcA,
                         const int* __restrict__ perm, const int* __restrict__ offsets,
                         const uint4* __restrict__ Wpk,    // [NPAIR] packed f16 w + f32 b
                         const float* __restrict__ root, const float* __restrict__ bias,
                         float* __restrict__ hnext) {      // [N][OSTR]
  constexpr int NPAIR = IN * OUT;
  constexpr int K_PER = (NPAIR + 63) / 64;
  constexpr int B = 32;
  constexpr int NW = 8;

  __shared__ unsigned eaS[NW][2][B][4];
  __shared__ int srcS[NW][2][B];
  __shared__ float pAcc[NW][NPAIR];

  const int tid = threadIdx.x;
  const int wid = tid >> 6;
  const int l = tid & 63;
  const int node = blockIdx.x;
  const int off = offsets[node];
  const int cnt = offsets[node + 1] - off;

  // ---- per-lane pair slice ----
  const int p0 = l * K_PER;
  const int i0 = min(p0, NPAIR - 1) / OUT;
  const int i1 = min(i0 + 1, IN - 1);
  const int kb = (i0 + 1) * OUT - p0;  // k < kb -> h[i0], else h[i1]
  uint4 wpk[K_PER];
  float acc[K_PER];
#pragma unroll
  for (int k = 0; k < K_PER; k++) {
    wpk[k] = Wpk[min(p0 + k, NPAIR - 1)];
    acc[k] = 0.f;
  }

  const int NB = (cnt + B - 1) / B;

  // ---- staging: ea (packed f16) + src into LDS; T14 split ----
  float2 la0, la1, la2;
  int lsrc;
  bool lok = false;

  auto stage_load = [&](int m) {
    const int pos = m * B + l;
    lok = (l < B) && (pos < cnt);
    if (lok) {
      const int e = perm[off + pos];
      const float2* er = reinterpret_cast<const float2*>(ea + (size_t)e * 6);
      la0 = er[0]; la1 = er[1]; la2 = er[2];
      lsrc = srcA[e];
    }
  };
  auto stage_write = [&](int buf) {
    if (lok) {
      uint4 pk;
      pk.x = pkf16(la0.x, la0.y);
      pk.y = pkf16(la1.x, la1.y);
      pk.z = pkf16(la2.x, la2.y);
      pk.w = 0u;
      *reinterpret_cast<uint4*>(&eaS[wid][buf][l][0]) = pk;
      srcS[wid][buf][l] = lsrc;
    }
  };

  if (wid < NB) { stage_load(wid); stage_write(0); }
  int buf = 0;
  for (int m = wid; m < NB; m += NW, buf ^= 1) {
    const bool more = (m + NW < NB);
    if (more) stage_load(m + NW);
    const int lim = min(B, cnt - m * B);
    // software-pipelined per-lane h gather (global, L1/L2)
    int sn = srcS[wid][buf][0];
    float h0n = hprev[(size_t)sn * HP + i0];
    float h1n = hprev[(size_t)sn * HP + i1];
    for (int b = 0; b < lim; b++) {
      const float hv0 = h0n, hv1 = h1n;
      if (b + 1 < lim) {
        sn = srcS[wid][buf][b + 1];
        h0n = hprev[(size_t)sn * HP + i0];
        h1n = hprev[(size_t)sn * HP + i1];
      }
      const uint4 eu = *reinterpret_cast<const uint4*>(&eaS[wid][buf][b][0]);
      const h2 a01 = ash2(eu.x), a23 = ash2(eu.y), a45 = ash2(eu.z);
#pragma unroll
      for (int k = 0; k < K_PER; k++) {
        float th = __builtin_bit_cast(float, wpk[k].w);
        th = fdot2(a01, ash2(wpk[k].x), th);
        th = fdot2(a23, ash2(wpk[k].y), th);
        th = fdot2(a45, ash2(wpk[k].z), th);
        const float hv = (k < kb) ? hv0 : hv1;
        acc[k] = fmaf(hv, fmaxf(th, 0.f), acc[k]);
      }
    }
    if (more) stage_write(buf ^ 1);
  }

  // ---- reduction: per-wave partials -> pair sums -> outputs ----
#pragma unroll
  for (int k = 0; k < K_PER; k++)
    if (p0 + k < NPAIR) pAcc[wid][p0 + k] = acc[k];
  __syncthreads();
  for (int p = tid; p < NPAIR; p += 512) {
    float s = 0.f;
#pragma unroll
    for (int w = 0; w < NW; w++) s += pAcc[w][p];
    pAcc[0][p] = s;
  }
  __syncthreads();
  if (tid < OUT) {
    const int o = tid;
    float s = 0.f;
    for (int i = 0; i < IN; i++) s += pAcc[0][i * OUT + o];
    const float agg = s / fmaxf((float)cnt, 1.f);
    float r = bias[o];
    for (int i = 0; i < IN; i++) r = fmaf(hprev[(size_t)node * HP + i], root[i * OUT + o], r);
    hnext[(size_t)node * OSTR + o] = fmaxf(agg + r, 0.f);
  }
}

// ---------------- CBT: pairwise L1 over h3 [512, 5] ----------------
__global__ void cbt_k(const float* __restrict__ h3, float* __restrict__ out) {
  __shared__ float sh[N_NODES * 5];
  for (int i = threadIdx.x; i < N_NODES * 5; i += blockDim.x) sh[i] = h3[i];
  __syncthreads();
  const int a = blockIdx.x;
  float ha0 = sh[a * 5 + 0], ha1 = sh[a * 5 + 1], ha2 = sh[a * 5 + 2],
        ha3 = sh[a * 5 + 3], ha4 = sh[a * 5 + 4];
  for (int b = threadIdx.x; b < N_NODES; b += blockDim.x) {
    float s = fabsf(sh[b * 5 + 0] - ha0) + fabsf(sh[b * 5 + 1] - ha1) +
              fabsf(sh[b * 5 + 2] - ha2) + fabsf(sh[b * 5 + 3] - ha3) +
              fabsf(sh[b * 5 + 4] - ha4);
    out[a * N_NODES + b] = s;
  }
}

extern "C" void kernel_launch(void* const* d_in, const int* in_sizes, int n_in,
                              void* d_out, int out_size, void* d_ws, size_t ws_size,
                              hipStream_t stream) {
  const float* x     = (const float*)d_in[0];
  const float* ea    = (const float*)d_in[1];
  const int*   ei    = (const int*)d_in[2];
  const float* W1    = (const float*)d_in[3];
  const float* b1    = (const float*)d_in[4];
  const float* root1 = (const float*)d_in[5];
  const float* bias1 = (const float*)d_in[6];
  const float* W2    = (const float*)d_in[7];
  const float* b2    = (const float*)d_in[8];
  const float* root2 = (const float*)d_in[9];
  const float* bias2 = (const float*)d_in[10];
  const float* W3    = (const float*)d_in[11];
  const float* b3    = (const float*)d_in[12];
  const float* root3 = (const float*)d_in[13];
  const float* bias3 = (const float*)d_in[14];

  const int* src = ei;
  const int* dst = ei + N_EDGES;

  char* ws = (char*)d_ws;
  int* counts  = (int*)(ws + 0);
  int* offsets = (int*)(ws + 8192);
  int* cursor  = (int*)(ws + 16384);
  int* perm    = (int*)(ws + 32768);                 // E ints = 1 MB
  float* h1    = (float*)(ws + 32768 + N_EDGES * 4); // [512][40]
  float* h2_   = h1 + N_NODES * 40;                  // [512][24]
  float* h3    = h2_ + N_NODES * 24;                 // [512][5]
  uint4* wpk2  = (uint4*)(h3 + N_NODES * 5 + 3);     // 864 uint4 (16B-aligned)
  uint4* wpk3  = wpk2 + 36 * 24;                     // 120 uint4

  zero_k<<<2, 256, 0, stream>>>(counts, N_NODES);
  hist_k<<<256, 256, 0, stream>>>(dst, counts);
  scan_k<<<1, N_NODES, 0, stream>>>(counts, offsets, cursor);
  scatter2_k<<<N_EDGES / 4096, 512, 0, stream>>>(dst, cursor, perm);
  packW_k<<<4, 256, 0, stream>>>(W2, b2, wpk2, 36 * 24);
  packW_k<<<1, 256, 0, stream>>>(W3, b3, wpk3, 24 * 5);

  // layer 1: IN=1 OUT=36, edge-parallel, output stride 40 (zero-padded)
  conv_k<1, 36, 1, 40><<<N_NODES, 256, 0, stream>>>(x, ea, src, perm, offsets, W1, b1, root1, bias1, h1);
  // layer 2: IN=36 (stride 40) OUT=24: 864 pairs across 64 lanes, 8 waves
  convR4_k<36, 40, 24, 24><<<N_NODES, 512, 0, stream>>>(h1, ea, src, perm, offsets, wpk2, root2, bias2, h2_);
  // layer 3: IN=24 OUT=5: 120 pairs, K_PER=2
  convR4_k<24, 24, 5, 5><<<N_NODES, 512, 0, stream>>>(h2_, ea, src, perm, offsets, wpk3, root3, bias3, h3);

  cbt_k<<<N_NODES, 256, 0, stream>>>(h3, (float*)d_out);
}